// Round 6
// baseline (128.390 us; speedup 1.0000x reference)
//
#include <hip/hip_runtime.h>
#include <hip/hip_fp16.h>

#define MM 16      // mixtures
#define DD 128     // visible dims
#define CC 50      // categories
#define BB 32768   // batch
#define NP 64      // d-pairs (DD/2)
#define CP 2500    // CC*CC combined categories
#define NBLK 512   // fused grid (co-resident: <=128 VGPR -> >=4 blocks/CU cap = 1024)

// ---------------------------------------------------------------------------
// Fused single-launch kernel.
// Phase A (prep): block bid owns (d01 = bid>>3, oct = bid&7). Wave-parallel
//   softmax (validated in r2/3/5) of the 32 (dloc,m) rows -> LDS bf16;
//   emit fp16 pair-table entries e in [oct*313, min(2500, oct*313+313)).
// Barrier: device-scope atomic counter (zeroed by host-side memset each call),
//   all 512 blocks co-resident by capacity math.
// Phase B (gather): 4 lanes per row, lane l owns mixtures 4l..4l+3; 64
//   pair-gathers per row; x int4s for g=0 preloaded BEFORE phase A to hide
//   HBM latency under the table build. logw recomputed per-thread (uniform).
// ---------------------------------------------------------------------------
__global__ __launch_bounds__(256, 4) void fused_kernel(
    const int* __restrict__ x,        // [B][D] int32
    const float* __restrict__ mw,     // [M]
    const float* __restrict__ cate,   // [M][D][C] f32
    unsigned int* ptab,               // [NP][CP][8] u32 (fp16 pairs), in d_ws
    unsigned int* bar,                // barrier counter, in d_ws (memset 0)
    float* __restrict__ out)          // [B]
{
    __shared__ unsigned short lp[2][CC][MM];   // bf16, 3200 B

    const int tid = threadIdx.x;
    const int bid = blockIdx.x;

    // ---- phase-B x preload (independent of phase A): 8 int4 = 32 d's ----
    const int l = tid & 3;            // mixture-quad
    const int r = tid >> 2;           // 0..63
    const int b = bid * 64 + r;
    const int4* __restrict__ xrow = (const int4*)(x + b * DD);
    int4 xpre[8];
    #pragma unroll
    for (int j = 0; j < 8; ++j) xpre[j] = xrow[j];

    // ================= phase A: build pair table =================
    const int d01  = bid >> 3;
    const int oct  = bid & 7;
    const int wv   = tid >> 6;        // 0..3
    const int lane = tid & 63;

    #pragma unroll
    for (int i = 0; i < 8; ++i) {
        int rr   = wv * 8 + i;        // 0..31
        int dloc = rr >> 4;
        int m    = rr & 15;
        const float* row = cate + (m * DD + 2 * d01 + dloc) * CC;
        float v = (lane < CC) ? row[lane] : -1e30f;

        float mx = v;
        #pragma unroll
        for (int off = 32; off; off >>= 1)
            mx = fmaxf(mx, __shfl_xor(mx, off, 64));
        float e = (lane < CC) ? __expf(v - mx) : 0.f;
        #pragma unroll
        for (int off = 32; off; off >>= 1)
            e += __shfl_xor(e, off, 64);
        float lse = mx + __logf(e);

        if (lane < CC) {
            unsigned int bits = __float_as_uint(v - lse);
            bits += 0x7fffu + ((bits >> 16) & 1u);   // RNE to bf16
            lp[dloc][lane][m] = (unsigned short)(bits >> 16);
        }
    }
    __syncthreads();

    const int e_beg = oct * 313;
    const int e_end = min(CP, e_beg + 313);
    for (int e = e_beg + tid; e < e_end; e += 256) {
        int c0 = e / 50;
        int c1 = e - c0 * 50;
        const uint4* r0 = (const uint4*)&lp[0][c0][0];   // 16 bf16 = 32 B
        const uint4* r1 = (const uint4*)&lp[1][c1][0];
        uint4 A0 = r0[0], A1 = r0[1];
        uint4 B0 = r1[0], B1 = r1[1];
        unsigned int Aw[8] = {A0.x, A0.y, A0.z, A0.w, A1.x, A1.y, A1.z, A1.w};
        unsigned int Bw[8] = {B0.x, B0.y, B0.z, B0.w, B1.x, B1.y, B1.z, B1.w};
        unsigned int P[8];
        #pragma unroll
        for (int w = 0; w < 8; ++w) {
            float lo = __uint_as_float(Aw[w] << 16)
                     + __uint_as_float(Bw[w] << 16);
            float hi = __uint_as_float(Aw[w] & 0xffff0000u)
                     + __uint_as_float(Bw[w] & 0xffff0000u);
            __half2 h = __floats2half2_rn(lo, hi);   // lo = m=2w, hi = m=2w+1
            __builtin_memcpy(&P[w], &h, 4);
        }
        uint4* dst = (uint4*)(ptab + (size_t)(d01 * CP + e) * 8);
        dst[0] = make_uint4(P[0], P[1], P[2], P[3]);
        dst[1] = make_uint4(P[4], P[5], P[6], P[7]);
    }

    // ================= device-scope barrier =================
    __threadfence();                  // make this thread's table stores visible
    __syncthreads();                  // all block threads fenced
    if (tid == 0) {
        __hip_atomic_fetch_add(bar, 1u, __ATOMIC_ACQ_REL, __HIP_MEMORY_SCOPE_AGENT);
        while (__hip_atomic_load(bar, __ATOMIC_ACQUIRE, __HIP_MEMORY_SCOPE_AGENT) < NBLK)
            __builtin_amdgcn_s_sleep(1);
    }
    __syncthreads();

    // ================= phase B: pair gather =================
    // uniform log-softmax denominator of mixture weights
    float mmx = -1e30f;
    #pragma unroll
    for (int k = 0; k < MM; ++k) mmx = fmaxf(mmx, mw[k]);
    float sw = 0.f;
    #pragma unroll
    for (int k = 0; k < MM; ++k) sw += __expf(mw[k] - mmx);
    float lsew = mmx + __logf(sw);

    const uint2* __restrict__ tp = (const uint2*)ptab;
    float a0 = 0.f, a1 = 0.f, a2 = 0.f, a3 = 0.f;

    auto consume8 = [&](const int4* xv, int gbase) {
        #pragma unroll
        for (int j = 0; j < 8; ++j) {
            int jj = gbase + j;
            int ca = xv[j].x * CC + xv[j].y;   // pair d01 = 2jj
            int cb = xv[j].z * CC + xv[j].w;   // pair d01 = 2jj+1
            uint2 ua = tp[((2 * jj)     * CP + ca) * 4 + l];
            uint2 ub = tp[((2 * jj + 1) * CP + cb) * 4 + l];
            __half2 h; float2 f;
            __builtin_memcpy(&h, &ua.x, 4); f = __half22float2(h); a0 += f.x; a1 += f.y;
            __builtin_memcpy(&h, &ua.y, 4); f = __half22float2(h); a2 += f.x; a3 += f.y;
            __builtin_memcpy(&h, &ub.x, 4); f = __half22float2(h); a0 += f.x; a1 += f.y;
            __builtin_memcpy(&h, &ub.y, 4); f = __half22float2(h); a2 += f.x; a3 += f.y;
        }
    };

    consume8(xpre, 0);                         // preloaded before phase A
    #pragma unroll 1
    for (int g = 1; g < 4; ++g) {
        int4 xv[8];
        #pragma unroll
        for (int j = 0; j < 8; ++j) xv[j] = xrow[g * 8 + j];
        consume8(xv, g * 8);
    }

    float l0 = a0 + mw[4 * l + 0] - lsew;
    float l1 = a1 + mw[4 * l + 1] - lsew;
    float l2 = a2 + mw[4 * l + 2] - lsew;
    float l3 = a3 + mw[4 * l + 3] - lsew;

    float mx = fmaxf(fmaxf(l0, l1), fmaxf(l2, l3));
    mx = fmaxf(mx, __shfl_xor(mx, 1, 64));
    mx = fmaxf(mx, __shfl_xor(mx, 2, 64));
    float e = __expf(l0 - mx) + __expf(l1 - mx) + __expf(l2 - mx) + __expf(l3 - mx);
    e += __shfl_xor(e, 1, 64);
    e += __shfl_xor(e, 2, 64);

    if (l == 0) out[b] = mx + __logf(e);
}

extern "C" void kernel_launch(void* const* d_in, const int* in_sizes, int n_in,
                              void* d_out, int out_size, void* d_ws, size_t ws_size,
                              hipStream_t stream) {
    const int*   x    = (const int*)d_in[0];     // [B][D]
    const float* mw   = (const float*)d_in[1];   // [M]
    const float* cate = (const float*)d_in[2];   // [M][D][C]
    float* out = (float*)d_out;

    unsigned int* ptab = (unsigned int*)d_ws;    // NP*CP*8 u32 = 5,120,000 B
    unsigned int* bar  = (unsigned int*)((char*)d_ws + (size_t)NP * CP * 8 * 4);

    hipMemsetAsync(bar, 0, 4, stream);           // reset barrier counter (capture-legal)
    fused_kernel<<<NBLK, 256, 0, stream>>>(x, mw, cate, ptab, bar, out);
}

// Round 7
// 75.061 us; speedup vs baseline: 1.7105x; 1.7105x over previous
//
#include <hip/hip_runtime.h>
#include <hip/hip_fp16.h>

#define MM 16      // mixtures
#define DD 128     // visible dims
#define CC 50      // categories
#define BB 32768   // batch
#define NP 64      // d-pairs (DD/2)
#define CP 2500    // CC*CC combined categories
#define NBLK 512   // fused grid; co-resident: 40 VGPR/3.6KB LDS -> capacity >= 2048 blocks

// ---------------------------------------------------------------------------
// Fused single-launch kernel (phases identical to validated round-5 math).
// Phase A: block (d01 = bid>>3, oct = bid&7): wave-parallel softmax of 32
//   (dloc,m) rows -> LDS bf16; emit fp16 pair-table slice (coalesced 32B).
// Barrier: RELAXED-poll global barrier. Release = one wbl2 per block;
//   spin = relaxed sc1 loads (NO per-poll cache invalidate -- round 6's
//   acquire-poll invalidation storm was the 110us pathology); acquire =
//   one buffer_inv per block after release observed.
// Phase B: pair gather, 4 lanes/row, 64 gathers/row; g=0 x-int4s preloaded
//   before phase A to hide HBM latency under table build.
// ---------------------------------------------------------------------------
__global__ __launch_bounds__(256, 4) void fused_kernel(
    const int* __restrict__ x,        // [B][D] int32
    const float* __restrict__ mw,     // [M]
    const float* __restrict__ cate,   // [M][D][C] f32
    unsigned int* ptab,               // [NP][CP][8] u32 (fp16 pairs), in d_ws
    unsigned int* bar,                // barrier counter, in d_ws (memset 0)
    float* __restrict__ out)          // [B]
{
    __shared__ unsigned short lp[2][CC][MM];   // bf16, 3200 B

    const int tid = threadIdx.x;
    const int bid = blockIdx.x;

    // ---- phase-B x preload (independent of phase A): 8 int4 = 32 d's ----
    const int l = tid & 3;            // mixture-quad
    const int r = tid >> 2;           // 0..63
    const int b = bid * 64 + r;
    const int4* __restrict__ xrow = (const int4*)(x + b * DD);
    int4 xpre[8];
    #pragma unroll
    for (int j = 0; j < 8; ++j) xpre[j] = xrow[j];

    // ================= phase A: build pair table =================
    const int d01  = bid >> 3;
    const int oct  = bid & 7;
    const int wv   = tid >> 6;        // 0..3
    const int lane = tid & 63;

    #pragma unroll
    for (int i = 0; i < 8; ++i) {
        int rr   = wv * 8 + i;        // 0..31
        int dloc = rr >> 4;
        int m    = rr & 15;
        const float* row = cate + (m * DD + 2 * d01 + dloc) * CC;
        float v = (lane < CC) ? row[lane] : -1e30f;

        float mx = v;
        #pragma unroll
        for (int off = 32; off; off >>= 1)
            mx = fmaxf(mx, __shfl_xor(mx, off, 64));
        float e = (lane < CC) ? __expf(v - mx) : 0.f;
        #pragma unroll
        for (int off = 32; off; off >>= 1)
            e += __shfl_xor(e, off, 64);
        float lse = mx + __logf(e);

        if (lane < CC) {
            unsigned int bits = __float_as_uint(v - lse);
            bits += 0x7fffu + ((bits >> 16) & 1u);   // RNE to bf16
            lp[dloc][lane][m] = (unsigned short)(bits >> 16);
        }
    }
    __syncthreads();

    const int e_beg = oct * 313;
    const int e_end = min(CP, e_beg + 313);
    for (int e = e_beg + tid; e < e_end; e += 256) {
        int c0 = e / 50;
        int c1 = e - c0 * 50;
        const uint4* r0 = (const uint4*)&lp[0][c0][0];   // 16 bf16 = 32 B
        const uint4* r1 = (const uint4*)&lp[1][c1][0];
        uint4 A0 = r0[0], A1 = r0[1];
        uint4 B0 = r1[0], B1 = r1[1];
        unsigned int Aw[8] = {A0.x, A0.y, A0.z, A0.w, A1.x, A1.y, A1.z, A1.w};
        unsigned int Bw[8] = {B0.x, B0.y, B0.z, B0.w, B1.x, B1.y, B1.z, B1.w};
        unsigned int P[8];
        #pragma unroll
        for (int w = 0; w < 8; ++w) {
            float lo = __uint_as_float(Aw[w] << 16)
                     + __uint_as_float(Bw[w] << 16);
            float hi = __uint_as_float(Aw[w] & 0xffff0000u)
                     + __uint_as_float(Bw[w] & 0xffff0000u);
            __half2 h = __floats2half2_rn(lo, hi);   // lo = m=2w, hi = m=2w+1
            __builtin_memcpy(&P[w], &h, 4);
        }
        uint4* dst = (uint4*)(ptab + (size_t)(d01 * CP + e) * 8);
        dst[0] = make_uint4(P[0], P[1], P[2], P[3]);
        dst[1] = make_uint4(P[4], P[5], P[6], P[7]);
    }

    // ================= device-scope barrier (relaxed-poll) =================
    __syncthreads();   // all block stores issued & vmcnt-drained (in XCD L2)
    if (tid == 0) {
        // push this block's ptab lines to the coherence point (one wbl2)
        __builtin_amdgcn_fence(__ATOMIC_RELEASE, "agent");
        __hip_atomic_fetch_add(bar, 1u, __ATOMIC_RELAXED, __HIP_MEMORY_SCOPE_AGENT);
        // relaxed sc1 polls: fresh reads, NO cache invalidate per iteration
        while (__hip_atomic_load(bar, __ATOMIC_RELAXED, __HIP_MEMORY_SCOPE_AGENT) < NBLK)
            __builtin_amdgcn_s_sleep(16);
        // one invalidate per block, after release observed
        __builtin_amdgcn_fence(__ATOMIC_ACQUIRE, "agent");
    }
    __syncthreads();

    // ================= phase B: pair gather =================
    float mmx = -1e30f;
    #pragma unroll
    for (int k = 0; k < MM; ++k) mmx = fmaxf(mmx, mw[k]);
    float sw = 0.f;
    #pragma unroll
    for (int k = 0; k < MM; ++k) sw += __expf(mw[k] - mmx);
    float lsew = mmx + __logf(sw);

    const uint2* __restrict__ tp = (const uint2*)ptab;
    float a0 = 0.f, a1 = 0.f, a2 = 0.f, a3 = 0.f;

    auto consume8 = [&](const int4* xv, int gbase) {
        #pragma unroll
        for (int j = 0; j < 8; ++j) {
            int jj = gbase + j;
            int ca = xv[j].x * CC + xv[j].y;   // pair d01 = 2jj
            int cb = xv[j].z * CC + xv[j].w;   // pair d01 = 2jj+1
            uint2 ua = tp[((2 * jj)     * CP + ca) * 4 + l];
            uint2 ub = tp[((2 * jj + 1) * CP + cb) * 4 + l];
            __half2 h; float2 f;
            __builtin_memcpy(&h, &ua.x, 4); f = __half22float2(h); a0 += f.x; a1 += f.y;
            __builtin_memcpy(&h, &ua.y, 4); f = __half22float2(h); a2 += f.x; a3 += f.y;
            __builtin_memcpy(&h, &ub.x, 4); f = __half22float2(h); a0 += f.x; a1 += f.y;
            __builtin_memcpy(&h, &ub.y, 4); f = __half22float2(h); a2 += f.x; a3 += f.y;
        }
    };

    consume8(xpre, 0);                         // preloaded before phase A
    #pragma unroll 1
    for (int g = 1; g < 4; ++g) {
        int4 xv[8];
        #pragma unroll
        for (int j = 0; j < 8; ++j) xv[j] = xrow[g * 8 + j];
        consume8(xv, g * 8);
    }

    float l0 = a0 + mw[4 * l + 0] - lsew;
    float l1 = a1 + mw[4 * l + 1] - lsew;
    float l2 = a2 + mw[4 * l + 2] - lsew;
    float l3 = a3 + mw[4 * l + 3] - lsew;

    float mx = fmaxf(fmaxf(l0, l1), fmaxf(l2, l3));
    mx = fmaxf(mx, __shfl_xor(mx, 1, 64));
    mx = fmaxf(mx, __shfl_xor(mx, 2, 64));
    float e = __expf(l0 - mx) + __expf(l1 - mx) + __expf(l2 - mx) + __expf(l3 - mx);
    e += __shfl_xor(e, 1, 64);
    e += __shfl_xor(e, 2, 64);

    if (l == 0) out[b] = mx + __logf(e);
}

extern "C" void kernel_launch(void* const* d_in, const int* in_sizes, int n_in,
                              void* d_out, int out_size, void* d_ws, size_t ws_size,
                              hipStream_t stream) {
    const int*   x    = (const int*)d_in[0];     // [B][D]
    const float* mw   = (const float*)d_in[1];   // [M]
    const float* cate = (const float*)d_in[2];   // [M][D][C]
    float* out = (float*)d_out;

    unsigned int* ptab = (unsigned int*)d_ws;    // NP*CP*8 u32 = 5,120,000 B
    unsigned int* bar  = (unsigned int*)((char*)d_ws + (size_t)NP * CP * 8 * 4);

    hipMemsetAsync(bar, 0, 4, stream);           // reset barrier counter (capture-legal)
    fused_kernel<<<NBLK, 256, 0, stream>>>(x, mw, cate, ptab, bar, out);
}

// Round 8
// 25.152 us; speedup vs baseline: 5.1045x; 2.9843x over previous
//
#include <hip/hip_runtime.h>
#include <hip/hip_bf16.h>

#define MM 16      // mixtures
#define DD 128     // visible dims
#define CC 50      // categories
#define BB 32768   // batch

// ---------------------------------------------------------------------------
// prep: one WAVE per (m,d) row (pattern validated r2/r3/r5). Lanes 0..49 load
// the 50 logits, shfl-reduce log_softmax, store bf16 (RNE) transposed to
// [D][C][M] so the 16 m-values of a (d,c) are one contiguous 32B block.
// 2048 waves total. No logw output (gather recomputes it uniformly).
// ---------------------------------------------------------------------------
__global__ __launch_bounds__(256) void prep_kernel(
    const float* __restrict__ cate,    // [M][D][C] f32
    unsigned short* __restrict__ tabw) // [D][C][M] bf16
{
    const int wid  = (blockIdx.x * 256 + threadIdx.x) >> 6;  // 0..2047
    const int lane = threadIdx.x & 63;
    const int m = wid >> 7;        // wid / DD
    const int d = wid & (DD - 1);  // wid % DD

    const float* row = cate + (m * DD + d) * CC;
    float v = (lane < CC) ? row[lane] : -1e30f;

    float mx = v;
    #pragma unroll
    for (int off = 32; off; off >>= 1)
        mx = fmaxf(mx, __shfl_xor(mx, off, 64));
    float e = (lane < CC) ? __expf(v - mx) : 0.f;
    #pragma unroll
    for (int off = 32; off; off >>= 1)
        e += __shfl_xor(e, off, 64);
    float lse = mx + __logf(e);

    if (lane < CC) {
        unsigned int bits = __float_as_uint(v - lse);
        bits += 0x7fffu + ((bits >> 16) & 1u);   // RNE to bf16
        tabw[(d * CC + lane) * MM + m] = (unsigned short)(bits >> 16);
    }
}

// ---------------------------------------------------------------------------
// gather: 8 lanes per batch row; lane h owns d in [16h, 16h+16) and ALL 16
// mixtures. Per (b,d) event: 2 adjacent dwordx4 loads (32B, one 64B line).
// Gather instrs: 4.2M events * 2 / 64 = 131K (4x fewer TA addresses than the
// 8-lane-per-event r2 layout). x loads: each int read by exactly one lane,
// coalesced across the wave. Partial a[m] sums combined over the 8-lane
// group via 3 xor-shfl rounds; logsumexp over m; lane h==0 stores.
// Block = 256 threads = 32 rows; grid = 1024 blocks (16 waves/CU).
// ---------------------------------------------------------------------------
__global__ __launch_bounds__(256) void gather_kernel(
    const int* __restrict__ x,        // [B][D] int32
    const uint4* __restrict__ tab,    // [D][C][2] uint4 (16 bf16 per (d,c))
    const float* __restrict__ mw,     // [M]
    float* __restrict__ out)          // [B]
{
    const int tid = threadIdx.x;
    const int h   = tid & 7;          // d-range owner
    const int r   = tid >> 3;         // 0..31
    const int b   = blockIdx.x * 32 + r;

    // uniform log-softmax denominator of mixture weights (r5-proven pattern)
    float mmx = -1e30f;
    #pragma unroll
    for (int k = 0; k < MM; ++k) mmx = fmaxf(mmx, mw[k]);
    float sw = 0.f;
    #pragma unroll
    for (int k = 0; k < MM; ++k) sw += __expf(mw[k] - mmx);
    float lsew = mmx + __logf(sw);

    const int4* __restrict__ xq = (const int4*)(x + b * DD) + h * 4;

    float a[MM];
    #pragma unroll
    for (int i = 0; i < MM; ++i) a[i] = 0.f;

    #pragma unroll
    for (int j = 0; j < 4; ++j) {
        int4 xv = xq[j];                       // x[b, 16h+4j .. 16h+4j+3]
        int cs[4] = { xv.x, xv.y, xv.z, xv.w };
        #pragma unroll
        for (int k = 0; k < 4; ++k) {
            int d = h * 16 + j * 4 + k;
            const uint4* p = tab + (size_t)(d * CC + cs[k]) * 2;
            uint4 u0 = p[0];                   // m = 0..7
            uint4 u1 = p[1];                   // m = 8..15
            unsigned int w[8] = { u0.x, u0.y, u0.z, u0.w,
                                  u1.x, u1.y, u1.z, u1.w };
            #pragma unroll
            for (int q = 0; q < 8; ++q) {
                a[2 * q]     += __uint_as_float(w[q] << 16);
                a[2 * q + 1] += __uint_as_float(w[q] & 0xffff0000u);
            }
        }
    }

    // combine the 8 d-range partials (xor 1,2,4 within the 8-lane group)
    #pragma unroll
    for (int off = 1; off < 8; off <<= 1) {
        #pragma unroll
        for (int i = 0; i < MM; ++i)
            a[i] += __shfl_xor(a[i], off, 64);
    }

    // logsumexp over the 16 mixtures (all 8 lanes redundantly; h==0 stores)
    float ll[MM];
    float mx = -1e30f;
    #pragma unroll
    for (int i = 0; i < MM; ++i) {
        ll[i] = a[i] + mw[i] - lsew;
        mx = fmaxf(mx, ll[i]);
    }
    float e = 0.f;
    #pragma unroll
    for (int i = 0; i < MM; ++i) e += __expf(ll[i] - mx);

    if (h == 0) out[b] = mx + __logf(e);
}

extern "C" void kernel_launch(void* const* d_in, const int* in_sizes, int n_in,
                              void* d_out, int out_size, void* d_ws, size_t ws_size,
                              hipStream_t stream) {
    const int*   x    = (const int*)d_in[0];     // [B][D]
    const float* mw   = (const float*)d_in[1];   // [M]
    const float* cate = (const float*)d_in[2];   // [M][D][C]
    float* out = (float*)d_out;

    unsigned short* tabw = (unsigned short*)d_ws;  // D*C*M bf16 = 204800 B

    // prep: one wave per (m,d) row -> 2048 waves (512 blocks x 4 waves)
    prep_kernel<<<(MM * DD) / 4, 256, 0, stream>>>(cate, tabw);

    // gather: 32 batch rows per 256-thread block
    gather_kernel<<<BB / 32, 256, 0, stream>>>(x, (const uint4*)tabw, mw, out);
}